// Round 1
// baseline (212.140 us; speedup 1.0000x reference)
//
#include <hip/hip_runtime.h>
#include <hip/hip_bf16.h>

// Problem constants
#define BATCH  128
#define HWN    196          // (224/16)^2 patches per sample
#define HIDN   768
#define KN     768          // 3*16*16
#define IMGSZ  224
#define IMG2   (224*224)
#define MTOT   (BATCH*HWN)  // 25088 output rows

// GEMM tiling (m97 structure, A-staging fused from x)
#define BM 128
#define BN 128
#define BK 32
#define NT  (KN/BK)         // 24 K-steps
#define NBM (MTOT/BM)       // 196
#define NBN (HIDN/BN)       // 6
#define NWG (NBM*NBN)       // 1176 = 8 * 147 exactly -> bijective XCD swizzle
#define CPX (NWG/8)         // 147

typedef __attribute__((ext_vector_type(8))) short bf16x8;
typedef __attribute__((ext_vector_type(4))) float floatx4;

#define GP(p) ((const __attribute__((address_space(1))) void*)(p))
#define SP(p) ((__attribute__((address_space(3))) void*)(p))

static __device__ __forceinline__ short f2bf(float f) {
    __hip_bfloat16 h = __float2bfloat16(f);   // RNE
    return __builtin_bit_cast(short, h);
}

static __device__ __forceinline__ bf16x8 cvt8v(float4 f0, float4 f1) {
    bf16x8 v;
    v[0]=f2bf(f0.x); v[1]=f2bf(f0.y); v[2]=f2bf(f0.z); v[3]=f2bf(f0.w);
    v[4]=f2bf(f1.x); v[5]=f2bf(f1.y); v[6]=f2bf(f1.z); v[7]=f2bf(f1.w);
    return v;
}

// ---------------------------------------------------------------------------
// prep_W: fp32 -> bf16, 768*768 elems, 8 per thread. 288 blocks of 256. ~2 us.
// ---------------------------------------------------------------------------
__global__ __launch_bounds__(256)
void prep_W(const float* __restrict__ W, unsigned short* __restrict__ Wb)
{
    const int idx = blockIdx.x * 256 + threadIdx.x;   // < 73728
    float4 f0 = *(const float4*)(W + (size_t)idx * 8);
    float4 f1 = *(const float4*)(W + (size_t)idx * 8 + 4);
    *(bf16x8*)(Wb + (size_t)idx * 8) = cvt8v(f0, f1);
}

// ---------------------------------------------------------------------------
// gemm_fused: C[r,n] = sum_k bf16(x_gathered)[r,k]*Wb[n,k] + bias[n]
// A is NOT materialized: each thread gathers its (row, 16-float seg) of the
// 128x32 A-tile straight from x (perm applied at load), converts to bf16 and
// ds_writes it. x-loads for tile t+1 are register-prefetched under tile t's
// MFMAs, so only cvt+ds_write (+L2-hit B glds) sit on the barrier path.
// LDS A layout: [128][32] bf16 rows (64 B), k-byte-offset XOR'd with
// ((row>>1)&1)<<4 on BOTH write and fragment-read sides (involution) to
// spread the explicit ds_write_b128s across all 8 16B-slot columns.
// ---------------------------------------------------------------------------
__global__ __launch_bounds__(256, 3)
void gemm_fused(const float* __restrict__ x, const int* __restrict__ perm,
                const unsigned short* __restrict__ Wb,
                const float* __restrict__ bias, float* __restrict__ out)
{
    __shared__ __align__(16) unsigned short As[BM * BK];  // 8 KB
    __shared__ __align__(16) unsigned short Bs[BN * BK];  // 8 KB

    const int tid = threadIdx.x;
    // XCD-bijective swizzle: each XCD gets 147 consecutive bm-major tiles, so
    // the 6 bn-tiles of one bm-panel share that XCD's L2 (x-panel read once).
    const int wg  = blockIdx.x;
    const int lid = (wg & 7) * CPX + (wg >> 3);
    const int bm  = lid / NBN;
    const int bn  = lid - bm * NBN;

    // ---- A staging coords: thread owns (row = tid>>1, 16-float seg = tid&1)
    const int arow = tid >> 1;
    const int aseg = tid & 1;
    const int gr   = bm * BM + arow;
    const int b    = gr / HWN;
    const int p    = perm[gr];
    const int py   = p / 14, px = p - py * 14;
    const float* xbase = x + (size_t)b * 3 * IMG2
                           + (size_t)(py * 16) * IMGSZ + px * 16;
    const int axor = ((arow >> 1) & 1) << 4;
    char* aw0 = (char*)As + arow * 64 + ((aseg * 32     ) ^ axor);
    char* aw1 = (char*)As + arow * 64 + ((aseg * 32 + 16) ^ axor);

    // ---- B staging: global_load_lds width=16, linear (Wb is L2-resident)
    const int srow = tid >> 2;
    const int sseg = tid & 3;
    const unsigned short* gb = Wb + (size_t)(bn * BN + srow) * KN + sseg * 8;

    // ---- fragment coords
    const int lane = tid & 63;
    const int wave = tid >> 6;
    const int wm = (wave >> 1) * 64;
    const int wn = (wave & 1) * 64;
    const int lr = lane & 15;
    const int lq = lane >> 4;
    const int ard = (lq * 16) ^ (((lr >> 1) & 1) << 4);  // swizzled afrag k-byte

    floatx4 acc[4][4] = {};
    float4 xf0, xf1, xf2, xf3;

    auto loadx = [&](int t) {
        const int s = t * 2 + aseg;               // global 16-float seg id 0..47
        const float* src = xbase + (s >> 4) * IMG2 + (s & 15) * IMGSZ;
        xf0 = *(const float4*)(src);
        xf1 = *(const float4*)(src + 4);
        xf2 = *(const float4*)(src + 8);
        xf3 = *(const float4*)(src + 12);
    };
    auto writea = [&]() {
        *(bf16x8*)aw0 = cvt8v(xf0, xf1);
        *(bf16x8*)aw1 = cvt8v(xf2, xf3);
    };
    auto gldsb = [&](int t) {
        __builtin_amdgcn_global_load_lds(GP(gb + t * BK),           SP(&Bs[tid * 8]),        16, 0, 0);
        __builtin_amdgcn_global_load_lds(GP(gb + 64 * KN + t * BK), SP(&Bs[2048 + tid * 8]), 16, 0, 0);
    };

    // prologue: stage tile 0
    loadx(0);
    gldsb(0);
    writea();
    __syncthreads();

    for (int t = 0; t < NT; ++t) {
        if (t + 1 < NT) loadx(t + 1);   // reg-prefetch next x segs under MFMA

        bf16x8 bfrag[4];
        #pragma unroll
        for (int j = 0; j < 4; ++j)
            bfrag[j] = *(const bf16x8*)&Bs[(wn + j * 16 + lr) * BK + lq * 8];
        #pragma unroll
        for (int i = 0; i < 4; ++i) {
            const bf16x8 afrag = *(const bf16x8*)((const char*)As + (wm + i * 16 + lr) * 64 + ard);
            #pragma unroll
            for (int j = 0; j < 4; ++j)
                acc[i][j] = __builtin_amdgcn_mfma_f32_16x16x32_bf16(
                                afrag, bfrag[j], acc[i][j], 0, 0, 0);
        }

        if (t + 1 < NT) {
            __syncthreads();            // all waves done reading As/Bs
            gldsb(t + 1);
            writea();                   // cvt waits on the prefetched xf regs
            __syncthreads();            // staging visible (vmcnt+lgkm drain)
        }
    }

    // epilogue: bias + store (C/D: col = lane&15, row = quad*4 + reg)
    #pragma unroll
    for (int j = 0; j < 4; ++j) {
        const int gc = bn * BN + wn + j * 16 + lr;
        const float bv = bias[gc];
        #pragma unroll
        for (int i = 0; i < 4; ++i) {
            const int grow = bm * BM + wm + i * 16 + lq * 4;
            float* op = out + (size_t)grow * HIDN + gc;
            #pragma unroll
            for (int r = 0; r < 4; ++r)
                op[(size_t)r * HIDN] = acc[i][j][r] + bv;
        }
    }
}

extern "C" void kernel_launch(void* const* d_in, const int* in_sizes, int n_in,
                              void* d_out, int out_size, void* d_ws, size_t ws_size,
                              hipStream_t stream) {
    const float* x    = (const float*)d_in[0];
    const float* W    = (const float*)d_in[1];
    const float* bias = (const float*)d_in[2];
    const int*   perm = (const int*)d_in[3];
    float* out = (float*)d_out;

    // workspace: only Wb bf16 [768*768] (1.2 MB) — A is never materialized
    unsigned short* Wb = (unsigned short*)d_ws;

    prep_W<<<dim3(KN * HIDN / 8 / 256), dim3(256), 0, stream>>>(W, Wb);
    gemm_fused<<<dim3(NWG), dim3(256), 0, stream>>>(x, perm, Wb, bias, out);
}